// Round 15
// baseline (613.718 us; speedup 1.0000x reference)
//
#include <hip/hip_runtime.h>
#include <stdint.h>

typedef _Float16 f16;
typedef unsigned short u16;
typedef __attribute__((ext_vector_type(8))) _Float16 h16x8;
typedef __attribute__((ext_vector_type(8))) unsigned short u16x8;
typedef __attribute__((ext_vector_type(4))) float f32x4;

#define NDIM  4096
#define KDIM  4096
#define LRDIM 64

__device__ __forceinline__ float bf2f(u16 b) {
  union { unsigned u; float f; } c; c.u = ((unsigned)b) << 16; return c.f;
}
__device__ __forceinline__ float h2f(u16 b) {
  union { u16 u; f16 h; } c; c.u = b; return (float)c.h;
}
__device__ __forceinline__ h16x8 pack8(float4 a, float4 b) {
  h16x8 w = { (f16)a.x, (f16)a.y, (f16)a.z, (f16)a.w,
              (f16)b.x, (f16)b.y, (f16)b.z, (f16)b.w };
  return w;
}

// async global->LDS, 16B/lane; true addrspacecast (proven green r10/r12/r14).
__device__ __forceinline__ void gll16(const void* g, void* l) {
  __builtin_amdgcn_global_load_lds(
      (const __attribute__((address_space(1))) void*)g,
      (__attribute__((address_space(3))) void*)l,
      16, 0, 0);
}

// ---------------------------------------------------------------------------
// frozen encoding classifier (proven): 0=f16, 1=bf16, 2=f32 halfword layout.
// ---------------------------------------------------------------------------
__device__ int frozen_mode(const void* frozen, int t) {
  const u16* fr = (const u16*)frozen;
  __shared__ int sE[256], sO[256];
  int ce = 0, co = 0;
  for (int j = 0; j < 8; ++j) {
    float ve = fabsf(bf2f(fr[t * 16 + 2 * j]));
    float vo = fabsf(bf2f(fr[t * 16 + 2 * j + 1]));
    if (ve >= 0.05f && ve <= 10.0f) ++ce;
    if (vo >= 0.05f && vo <= 10.0f) ++co;
  }
  sE[t] = ce; sO[t] = co;
  __syncthreads();
  for (int s = 128; s > 0; s >>= 1) {
    if (t < s) { sE[t] += sE[t + s]; sO[t] += sO[t + s]; }
    __syncthreads();
  }
  int te = sE[0], to = sO[0];
  __syncthreads();
  if (to > 1024) return (te > 1024) ? 1 : 2;
  return 0;
}

__device__ __forceinline__ h16x8 build_m8(
    const void* __restrict__ frozen, const float* __restrict__ gs,
    const float* __restrict__ gb, const float* __restrict__ sa,
    int o, int i0, int mode)
{
  size_t fo = (size_t)o * KDIM + i0;
  int gidx = (o >> 3) * 512 + (i0 >> 3);
  float gsf = gs[gidx], gbf = gb[gidx];
  float4 s0 = ((const float4*)(sa + fo))[0];
  float4 s1 = ((const float4*)(sa + fo))[1];
  float sv[8] = { s0.x, s0.y, s0.z, s0.w, s1.x, s1.y, s1.z, s1.w };
  float fv[8];
  if (mode == 2) {
    float4 q0 = ((const float4*)((const float*)frozen + fo))[0];
    float4 q1 = ((const float4*)((const float*)frozen + fo))[1];
    fv[0]=q0.x; fv[1]=q0.y; fv[2]=q0.z; fv[3]=q0.w;
    fv[4]=q1.x; fv[5]=q1.y; fv[6]=q1.z; fv[7]=q1.w;
  } else {
    u16x8 fb = *(const u16x8*)((const u16*)frozen + fo);
#pragma unroll
    for (int j = 0; j < 8; ++j) fv[j] = (mode == 1) ? bf2f(fb[j]) : h2f(fb[j]);
  }
  h16x8 w;
#pragma unroll
  for (int j = 0; j < 8; ++j) w[j] = (f16)(gbf + fv[j] * gsf + sv[j]);
  return w;
}

// ---------------------------------------------------------------------------
// k9_build_m (proven, unchanged)
// ---------------------------------------------------------------------------
__global__ __launch_bounds__(256) void k9_build_m(
    const void* __restrict__ frozen, const float* __restrict__ gs,
    const float* __restrict__ gb, const float* __restrict__ sa,
    f16* __restrict__ mW)
{
  int mode = frozen_mode(frozen, threadIdx.x);
  int idx = blockIdx.x * 256 + threadIdx.x;
  int o  = idx >> 9;
  int ig = idx & 511;
  h16x8 w = build_m8(frozen, gs, gb, sa, o, ig * 8, mode);
  *(h16x8*)(mW + (size_t)o * KDIM + ig * 8) = w;
}

// ---------------------------------------------------------------------------
// k15_hid: fuses cast_x + hid. 256 blocks (full-CU BW, fixing r12's 64-block
// mistake). BM=32 rows/block; A reg-staged from f32 x, packed once, written
// to BOTH LDS and xh (each (row,kchunk) covered exactly once grid-wide);
// B reg-staged from f32 L1 (1MB, L2-resident). Wave tile 16x32, dbuf, BK=32.
// ---------------------------------------------------------------------------
__global__ __launch_bounds__(256) void k15_hid(const float* __restrict__ x,
                                               const float* __restrict__ L1,
                                               f16* __restrict__ hid,
                                               f16* __restrict__ xh)
{
  __shared__ f16 sA[2][32 * 32];    // 2 KB per buf
  __shared__ f16 sB[2][64 * 32];    // 4 KB per buf
  int t = threadIdx.x;
  int l = t & 63, wid = t >> 6;
  int wr = wid >> 1, wc = wid & 1;  // wave tile: rows wr*16, cols wc*32
  int brow = blockIdx.x * 32;
  int ar = t >> 2, ac8 = (t & 3) * 8;   // A: threads 0..127 -> rows 0..31
  int brw = t >> 2, bc8 = (t & 3) * 8;  // B: 64 rows x 32 cols, 8/thread

  f32x4 acc[2] = {};

  {
    if (t < 128) {
      const float* ap = x + (size_t)(brow + ar) * KDIM + ac8;
      h16x8 wa = pack8(((const float4*)ap)[0], ((const float4*)ap)[1]);
      *(h16x8*)&sA[0][ar * 32 + ac8] = wa;
      *(h16x8*)(xh + (size_t)(brow + ar) * KDIM + ac8) = wa;
    }
    const float* lp = L1 + (size_t)brw * KDIM + bc8;
    *(h16x8*)&sB[0][brw * 32 + bc8] = pack8(((const float4*)lp)[0], ((const float4*)lp)[1]);
  }

  int cur = 0;
  const int NT = KDIM / 32;
  for (int kt = 0; kt < NT; ++kt) {
    __syncthreads();
    bool pf = (kt + 1 < NT);
    h16x8 wa, wb;
    if (pf) {
      int k0 = (kt + 1) * 32;
      if (t < 128) {
        const float* ap = x + (size_t)(brow + ar) * KDIM + k0 + ac8;
        wa = pack8(((const float4*)ap)[0], ((const float4*)ap)[1]);
        *(h16x8*)(xh + (size_t)(brow + ar) * KDIM + k0 + ac8) = wa;
      }
      const float* lp = L1 + (size_t)brw * KDIM + k0 + bc8;
      wb = pack8(((const float4*)lp)[0], ((const float4*)lp)[1]);
    }
    h16x8 aF, bF[2];
    aF = *(const h16x8*)&sA[cur][(wr * 16 + (l & 15)) * 32 + (l >> 4) * 8];
#pragma unroll
    for (int n = 0; n < 2; ++n)
      bF[n] = *(const h16x8*)&sB[cur][(wc * 32 + n * 16 + (l & 15)) * 32 + (l >> 4) * 8];
#pragma unroll
    for (int n = 0; n < 2; ++n)
      acc[n] = __builtin_amdgcn_mfma_f32_16x16x32_f16(aF, bF[n], acc[n], 0, 0, 0);
    if (pf) {
      if (t < 128)
        *(h16x8*)&sA[cur ^ 1][ar * 32 + ac8] = wa;
      *(h16x8*)&sB[cur ^ 1][brw * 32 + bc8] = wb;
    }
    cur ^= 1;
  }

#pragma unroll
  for (int n = 0; n < 2; ++n)
#pragma unroll
    for (int j = 0; j < 4; ++j) {
      int r = wr * 16 + ((l >> 4) << 2) + j;
      int c = wc * 32 + n * 16 + (l & 15);
      hid[(size_t)(brow + r) * LRDIM + c] = (f16)acc[n][j];
    }
}

// ---------------------------------------------------------------------------
// k16_main: r14's proven k12_main with __launch_bounds__(256, 4).
// 4 waves/SIMD bucket caps VGPR at 128 (current use 84 -> codegen expected
// UNCHANGED, unlike r13's (256,5) which hit the 64-VGPR bucket and spilled);
// pure occupancy headroom 3 -> 4 blocks/CU.
// ---------------------------------------------------------------------------
__global__ __launch_bounds__(256, 4) void k16_main(
    const f16* __restrict__ xh, const f16* __restrict__ mW,
    const f16* __restrict__ hid, const float* __restrict__ L2,
    const float* __restrict__ scale, const float* __restrict__ bias,
    float* __restrict__ out)
{
  __shared__ f16 sA[2][128 * 32];
  __shared__ f16 sB[2][128 * 32];
  int t = threadIdx.x;
  int l = t & 63, wid = t >> 6;
  int wr = wid >> 1, wc = wid & 1;

  int wg = blockIdx.x;
  int cpx = gridDim.x >> 3;
  int swz = (wg & 7) * cpx + (wg >> 3);
  int bm = swz & 63;
  int bn = swz >> 6;
  int brow = bm * 128, bcol = bn * 128;

  int ur = t >> 2, uc8 = (t & 3) * 8;

  f32x4 acc[4][4] = {};

  gll16(xh + (size_t)(brow + ur) * KDIM + uc8,      &sA[0][ur * 32 + uc8]);
  gll16(xh + (size_t)(brow + ur + 64) * KDIM + uc8, &sA[0][(ur + 64) * 32 + uc8]);
  gll16(mW + (size_t)(bcol + ur) * KDIM + uc8,      &sB[0][ur * 32 + uc8]);
  gll16(mW + (size_t)(bcol + ur + 64) * KDIM + uc8, &sB[0][(ur + 64) * 32 + uc8]);

  int cur = 0;
  const int NT = KDIM / 32;
  for (int kt = 0; kt < NT; ++kt) {
    __syncthreads();
    if (kt + 1 < NT) {
      int k0 = (kt + 1) * 32;
      gll16(xh + (size_t)(brow + ur) * KDIM + k0 + uc8,      &sA[cur ^ 1][ur * 32 + uc8]);
      gll16(xh + (size_t)(brow + ur + 64) * KDIM + k0 + uc8, &sA[cur ^ 1][(ur + 64) * 32 + uc8]);
      gll16(mW + (size_t)(bcol + ur) * KDIM + k0 + uc8,      &sB[cur ^ 1][ur * 32 + uc8]);
      gll16(mW + (size_t)(bcol + ur + 64) * KDIM + k0 + uc8, &sB[cur ^ 1][(ur + 64) * 32 + uc8]);
    }
    h16x8 aF[4], bF[4];
#pragma unroll
    for (int m = 0; m < 4; ++m)
      aF[m] = *(const h16x8*)&sA[cur][(wr * 64 + m * 16 + (l & 15)) * 32 + (l >> 4) * 8];
#pragma unroll
    for (int n = 0; n < 4; ++n)
      bF[n] = *(const h16x8*)&sB[cur][(wc * 64 + n * 16 + (l & 15)) * 32 + (l >> 4) * 8];
#pragma unroll
    for (int m = 0; m < 4; ++m)
#pragma unroll
      for (int n = 0; n < 4; ++n)
        acc[m][n] = __builtin_amdgcn_mfma_f32_16x16x32_f16(aF[m], bF[n], acc[m][n], 0, 0, 0);
    cur ^= 1;
  }

  // ---- fused epilogue, m-sliced (r11/r12/r14 proven, verbatim) ----
  __syncthreads();
  f16* sH = &sA[0][0];
  f16* sL = &sB[0][0];

  for (int j = 0; j < 4; ++j) {
    int u = t + j * 256;
    int r = u >> 3, c8 = (u & 7) * 8;
    *(h16x8*)&sH[r * 64 + c8] =
        *(const h16x8*)(hid + (size_t)(brow + r) * LRDIM + c8);
    const float* lp = L2 + (size_t)(bcol + r) * LRDIM + c8;
    *(h16x8*)&sL[r * 64 + c8] = pack8(((const float4*)lp)[0], ((const float4*)lp)[1]);
  }
  __syncthreads();

  float sc[4], bi[4];
#pragma unroll
  for (int n = 0; n < 4; ++n) {
    int o = bcol + wc * 64 + n * 16 + (l & 15);
    sc[n] = scale[o];
    bi[n] = bias[o];
  }

  // pass 1: mul = hid @ L2[0:4096]^T + scale ; acc <- mul * acc
  {
    h16x8 lB[4][2];
#pragma unroll
    for (int n = 0; n < 4; ++n)
#pragma unroll
      for (int kk = 0; kk < 2; ++kk)
        lB[n][kk] = *(const h16x8*)&sL[(wc * 64 + n * 16 + (l & 15)) * 64 + kk * 32 + (l >> 4) * 8];
#pragma unroll
    for (int m = 0; m < 4; ++m) {
      h16x8 hA0 = *(const h16x8*)&sH[(wr * 64 + m * 16 + (l & 15)) * 64 + (l >> 4) * 8];
      h16x8 hA1 = *(const h16x8*)&sH[(wr * 64 + m * 16 + (l & 15)) * 64 + 32 + (l >> 4) * 8];
      f32x4 mm[4];
#pragma unroll
      for (int n = 0; n < 4; ++n) {
        f32x4 mi = { sc[n], sc[n], sc[n], sc[n] };
        mm[n] = mi;
      }
#pragma unroll
      for (int n = 0; n < 4; ++n) {
        mm[n] = __builtin_amdgcn_mfma_f32_16x16x32_f16(hA0, lB[n][0], mm[n], 0, 0, 0);
        mm[n] = __builtin_amdgcn_mfma_f32_16x16x32_f16(hA1, lB[n][1], mm[n], 0, 0, 0);
      }
#pragma unroll
      for (int n = 0; n < 4; ++n)
        acc[m][n] *= mm[n];
    }
  }

  __syncthreads();
  for (int j = 0; j < 4; ++j) {
    int u = t + j * 256;
    int r = u >> 3, c8 = (u & 7) * 8;
    const float* lp = L2 + (size_t)(NDIM + bcol + r) * LRDIM + c8;
    *(h16x8*)&sL[r * 64 + c8] = pack8(((const float4*)lp)[0], ((const float4*)lp)[1]);
  }
  __syncthreads();

  // pass 2: add = hid @ L2[4096:8192]^T + bias ; out = add + acc
  {
    h16x8 lB[4][2];
#pragma unroll
    for (int n = 0; n < 4; ++n)
#pragma unroll
      for (int kk = 0; kk < 2; ++kk)
        lB[n][kk] = *(const h16x8*)&sL[(wc * 64 + n * 16 + (l & 15)) * 64 + kk * 32 + (l >> 4) * 8];
#pragma unroll
    for (int m = 0; m < 4; ++m) {
      h16x8 hA0 = *(const h16x8*)&sH[(wr * 64 + m * 16 + (l & 15)) * 64 + (l >> 4) * 8];
      h16x8 hA1 = *(const h16x8*)&sH[(wr * 64 + m * 16 + (l & 15)) * 64 + 32 + (l >> 4) * 8];
      f32x4 aa[4];
#pragma unroll
      for (int n = 0; n < 4; ++n) {
        f32x4 mi = { bi[n], bi[n], bi[n], bi[n] };
        aa[n] = mi;
      }
#pragma unroll
      for (int n = 0; n < 4; ++n) {
        aa[n] = __builtin_amdgcn_mfma_f32_16x16x32_f16(hA0, lB[n][0], aa[n], 0, 0, 0);
        aa[n] = __builtin_amdgcn_mfma_f32_16x16x32_f16(hA1, lB[n][1], aa[n], 0, 0, 0);
      }
      int rbase = brow + wr * 64 + m * 16 + ((l >> 4) << 2);
#pragma unroll
      for (int n = 0; n < 4; ++n) {
        int c = bcol + wc * 64 + n * 16 + (l & 15);
        f32x4 v = aa[n] + acc[m][n];
#pragma unroll
        for (int j = 0; j < 4; ++j)
          out[(size_t)(rbase + j) * NDIM + c] = v[j];
      }
    }
  }
}

// ---------------------------------------------------------------------------
extern "C" void kernel_launch(void* const* d_in, const int* in_sizes, int n_in,
                              void* d_out, int out_size, void* d_ws, size_t ws_size,
                              hipStream_t stream)
{
  const int SD[9] = {33554432,16777216,262144,524288,262144,262144,16777216,4096,4096};
  const int SA[9] = {4096,16777216,262144,262144,262144,524288,4096,16777216,33554432};
  bool dict = (n_in == 9), alph = (n_in == 9);
  if (n_in == 9) {
    for (int i = 0; i < 9; ++i) {
      if (in_sizes[i] != SD[i]) dict = false;
      if (in_sizes[i] != SA[i]) alph = false;
    }
  }
  if (!dict && !alph) {
    int ix = 0;
    for (int i = 0; i < n_in; ++i)
      if (in_sizes[i] == 33554432 || in_sizes[i] == 134217728) { ix = i; break; }
    dict = (ix == 0);
  }
  const float* x     = (const float*)d_in[dict ? 0 : 8];
  const void*  fr    =               d_in[1];
  const float* L1    = (const float*)d_in[dict ? 2 : 4];
  const float* L2    = (const float*)d_in[dict ? 3 : 5];
  const float* gs    = (const float*)d_in[dict ? 4 : 3];
  const float* gb    = (const float*)d_in[dict ? 5 : 2];
  const float* sa    = (const float*)d_in[dict ? 6 : 7];
  const float* scale = (const float*)d_in[dict ? 7 : 6];
  const float* bias  = (const float*)d_in[dict ? 8 : 0];
  float* out = (float*)d_out;

  const size_t MW_B = (size_t)NDIM * KDIM * 2;    // 33,554,432
  const size_t XH_B = (size_t)8192 * KDIM * 2;    // 67,108,864

  char* ws = (char*)d_ws;
  // ws_size proven >= this layout by rounds 9-14 (T2 path executed).
  f16* mW  = (f16*)ws;
  f16* xh  = (f16*)(ws + MW_B);
  f16* hid = (f16*)(ws + MW_B + XH_B);

  k9_build_m<<<dim3(8192), dim3(256), 0, stream>>>(fr, gs, gb, sa, mW);
  k15_hid<<<dim3(256), dim3(256), 0, stream>>>(x, L1, hid, xh);
  k16_main<<<dim3(2048), dim3(256), 0, stream>>>(
      xh, mW, hid, L2, scale, bias, out);
}

// Round 16
// 501.916 us; speedup vs baseline: 1.2228x; 1.2228x over previous
//
#include <hip/hip_runtime.h>
#include <stdint.h>

typedef _Float16 f16;
typedef unsigned short u16;
typedef __attribute__((ext_vector_type(8))) _Float16 h16x8;
typedef __attribute__((ext_vector_type(8))) unsigned short u16x8;
typedef __attribute__((ext_vector_type(4))) float f32x4;

#define NDIM  4096
#define KDIM  4096
#define LRDIM 64

__device__ __forceinline__ float bf2f(u16 b) {
  union { unsigned u; float f; } c; c.u = ((unsigned)b) << 16; return c.f;
}
__device__ __forceinline__ float h2f(u16 b) {
  union { u16 u; f16 h; } c; c.u = b; return (float)c.h;
}
__device__ __forceinline__ h16x8 pack8(float4 a, float4 b) {
  h16x8 w = { (f16)a.x, (f16)a.y, (f16)a.z, (f16)a.w,
              (f16)b.x, (f16)b.y, (f16)b.z, (f16)b.w };
  return w;
}

// async global->LDS, 16B/lane; true addrspacecast (proven green r10/r12/r14).
__device__ __forceinline__ void gll16(const void* g, void* l) {
  __builtin_amdgcn_global_load_lds(
      (const __attribute__((address_space(1))) void*)g,
      (__attribute__((address_space(3))) void*)l,
      16, 0, 0);
}

// ---------------------------------------------------------------------------
// frozen encoding classifier (proven): 0=f16, 1=bf16, 2=f32 halfword layout.
// ---------------------------------------------------------------------------
__device__ int frozen_mode(const void* frozen, int t) {
  const u16* fr = (const u16*)frozen;
  __shared__ int sE[256], sO[256];
  int ce = 0, co = 0;
  for (int j = 0; j < 8; ++j) {
    float ve = fabsf(bf2f(fr[t * 16 + 2 * j]));
    float vo = fabsf(bf2f(fr[t * 16 + 2 * j + 1]));
    if (ve >= 0.05f && ve <= 10.0f) ++ce;
    if (vo >= 0.05f && vo <= 10.0f) ++co;
  }
  sE[t] = ce; sO[t] = co;
  __syncthreads();
  for (int s = 128; s > 0; s >>= 1) {
    if (t < s) { sE[t] += sE[t + s]; sO[t] += sO[t + s]; }
    __syncthreads();
  }
  int te = sE[0], to = sO[0];
  __syncthreads();
  if (to > 1024) return (te > 1024) ? 1 : 2;
  return 0;
}

__device__ __forceinline__ h16x8 build_m8(
    const void* __restrict__ frozen, const float* __restrict__ gs,
    const float* __restrict__ gb, const float* __restrict__ sa,
    int o, int i0, int mode)
{
  size_t fo = (size_t)o * KDIM + i0;
  int gidx = (o >> 3) * 512 + (i0 >> 3);
  float gsf = gs[gidx], gbf = gb[gidx];
  float4 s0 = ((const float4*)(sa + fo))[0];
  float4 s1 = ((const float4*)(sa + fo))[1];
  float sv[8] = { s0.x, s0.y, s0.z, s0.w, s1.x, s1.y, s1.z, s1.w };
  float fv[8];
  if (mode == 2) {
    float4 q0 = ((const float4*)((const float*)frozen + fo))[0];
    float4 q1 = ((const float4*)((const float*)frozen + fo))[1];
    fv[0]=q0.x; fv[1]=q0.y; fv[2]=q0.z; fv[3]=q0.w;
    fv[4]=q1.x; fv[5]=q1.y; fv[6]=q1.z; fv[7]=q1.w;
  } else {
    u16x8 fb = *(const u16x8*)((const u16*)frozen + fo);
#pragma unroll
    for (int j = 0; j < 8; ++j) fv[j] = (mode == 1) ? bf2f(fb[j]) : h2f(fb[j]);
  }
  h16x8 w;
#pragma unroll
  for (int j = 0; j < 8; ++j) w[j] = (f16)(gbf + fv[j] * gsf + sv[j]);
  return w;
}

// ---------------------------------------------------------------------------
// k9_build_m / k9_cast_x (proven, unchanged)
// ---------------------------------------------------------------------------
__global__ __launch_bounds__(256) void k9_build_m(
    const void* __restrict__ frozen, const float* __restrict__ gs,
    const float* __restrict__ gb, const float* __restrict__ sa,
    f16* __restrict__ mW)
{
  int mode = frozen_mode(frozen, threadIdx.x);
  int idx = blockIdx.x * 256 + threadIdx.x;
  int o  = idx >> 9;
  int ig = idx & 511;
  h16x8 w = build_m8(frozen, gs, gb, sa, o, ig * 8, mode);
  *(h16x8*)(mW + (size_t)o * KDIM + ig * 8) = w;
}

__global__ __launch_bounds__(256) void k9_cast_x(const float* __restrict__ x,
                                                 f16* __restrict__ xh)
{
  size_t idx = (size_t)blockIdx.x * 256 + threadIdx.x;
  const float4* xp = (const float4*)x + idx * 2;
  *(h16x8*)(xh + idx * 8) = pack8(xp[0], xp[1]);
}

// ---------------------------------------------------------------------------
// k14_hid (proven r14): hid = xh @ L1^T via MFMA, 256 blocks, BM=32.
// ---------------------------------------------------------------------------
__global__ __launch_bounds__(256) void k14_hid(const f16* __restrict__ xh,
                                               const float* __restrict__ L1,
                                               f16* __restrict__ hid)
{
  __shared__ f16 sA[2][32 * 32];
  __shared__ f16 sB[2][64 * 32];
  int t = threadIdx.x;
  int l = t & 63, wid = t >> 6;
  int wr = wid >> 1, wc = wid & 1;
  int brow = blockIdx.x * 32;
  int ar = t >> 2, ac8 = (t & 3) * 8;
  int brw = t >> 2, bc8 = (t & 3) * 8;

  f32x4 acc[2] = {};

  {
    if (t < 128)
      gll16(xh + (size_t)(brow + ar) * KDIM + ac8, &sA[0][ar * 32 + ac8]);
    const float* lp = L1 + (size_t)brw * KDIM + bc8;
    *(h16x8*)&sB[0][brw * 32 + bc8] = pack8(((const float4*)lp)[0], ((const float4*)lp)[1]);
  }

  int cur = 0;
  const int NT = KDIM / 32;
  for (int kt = 0; kt < NT; ++kt) {
    __syncthreads();
    bool pf = (kt + 1 < NT);
    h16x8 wb;
    if (pf) {
      int k0 = (kt + 1) * 32;
      if (t < 128)
        gll16(xh + (size_t)(brow + ar) * KDIM + k0 + ac8, &sA[cur ^ 1][ar * 32 + ac8]);
      const float* lp = L1 + (size_t)brw * KDIM + k0 + bc8;
      wb = pack8(((const float4*)lp)[0], ((const float4*)lp)[1]);
    }
    h16x8 aF, bF[2];
    aF = *(const h16x8*)&sA[cur][(wr * 16 + (l & 15)) * 32 + (l >> 4) * 8];
#pragma unroll
    for (int n = 0; n < 2; ++n)
      bF[n] = *(const h16x8*)&sB[cur][(wc * 32 + n * 16 + (l & 15)) * 32 + (l >> 4) * 8];
#pragma unroll
    for (int n = 0; n < 2; ++n)
      acc[n] = __builtin_amdgcn_mfma_f32_16x16x32_f16(aF, bF[n], acc[n], 0, 0, 0);
    if (pf)
      *(h16x8*)&sB[cur ^ 1][brw * 32 + bc8] = wb;
    cur ^= 1;
  }

#pragma unroll
  for (int n = 0; n < 2; ++n)
#pragma unroll
    for (int j = 0; j < 4; ++j) {
      int r = wr * 16 + ((l >> 4) << 2) + j;
      int c = wc * 32 + n * 16 + (l & 15);
      hid[(size_t)(brow + r) * LRDIM + c] = (f16)acc[n][j];
    }
}

// ---------------------------------------------------------------------------
// k17_main: r14's proven k12_main ((256,3), 84 VGPR, no spill) with ONE
// change: 2-D chunked XCD mapping. Old 1-D swizzle gave each XCD all 64 xh
// panels (64MB active set -> L2/L3 thrash, FETCH 1.1GB vs 100MB unique).
// New: XCD x owns the 8bm x 32bn region (bm = 8x + (w&7), bn = w>>3;
// bijective since 2048 = 8*256). Per-XCD active set: 8MB xh + 1MB mW panel.
// ---------------------------------------------------------------------------
__global__ __launch_bounds__(256, 3) void k17_main(
    const f16* __restrict__ xh, const f16* __restrict__ mW,
    const f16* __restrict__ hid, const float* __restrict__ L2,
    const float* __restrict__ scale, const float* __restrict__ bias,
    float* __restrict__ out)
{
  __shared__ f16 sA[2][128 * 32];
  __shared__ f16 sB[2][128 * 32];
  int t = threadIdx.x;
  int l = t & 63, wid = t >> 6;
  int wr = wid >> 1, wc = wid & 1;

  // 2-D chunked XCD mapping (bijective: 2048 blocks = 8 XCDs x 256)
  int wg = blockIdx.x;
  int xcd = wg & 7;
  int w = wg >> 3;                  // 0..255 within XCD
  int bm = xcd * 8 + (w & 7);       // 0..63
  int bn = w >> 3;                  // 0..31
  int brow = bm * 128, bcol = bn * 128;

  int ur = t >> 2, uc8 = (t & 3) * 8;

  f32x4 acc[4][4] = {};

  gll16(xh + (size_t)(brow + ur) * KDIM + uc8,      &sA[0][ur * 32 + uc8]);
  gll16(xh + (size_t)(brow + ur + 64) * KDIM + uc8, &sA[0][(ur + 64) * 32 + uc8]);
  gll16(mW + (size_t)(bcol + ur) * KDIM + uc8,      &sB[0][ur * 32 + uc8]);
  gll16(mW + (size_t)(bcol + ur + 64) * KDIM + uc8, &sB[0][(ur + 64) * 32 + uc8]);

  int cur = 0;
  const int NT = KDIM / 32;
  for (int kt = 0; kt < NT; ++kt) {
    __syncthreads();
    if (kt + 1 < NT) {
      int k0 = (kt + 1) * 32;
      gll16(xh + (size_t)(brow + ur) * KDIM + k0 + uc8,      &sA[cur ^ 1][ur * 32 + uc8]);
      gll16(xh + (size_t)(brow + ur + 64) * KDIM + k0 + uc8, &sA[cur ^ 1][(ur + 64) * 32 + uc8]);
      gll16(mW + (size_t)(bcol + ur) * KDIM + k0 + uc8,      &sB[cur ^ 1][ur * 32 + uc8]);
      gll16(mW + (size_t)(bcol + ur + 64) * KDIM + k0 + uc8, &sB[cur ^ 1][(ur + 64) * 32 + uc8]);
    }
    h16x8 aF[4], bF[4];
#pragma unroll
    for (int m = 0; m < 4; ++m)
      aF[m] = *(const h16x8*)&sA[cur][(wr * 64 + m * 16 + (l & 15)) * 32 + (l >> 4) * 8];
#pragma unroll
    for (int n = 0; n < 4; ++n)
      bF[n] = *(const h16x8*)&sB[cur][(wc * 64 + n * 16 + (l & 15)) * 32 + (l >> 4) * 8];
#pragma unroll
    for (int m = 0; m < 4; ++m)
#pragma unroll
      for (int n = 0; n < 4; ++n)
        acc[m][n] = __builtin_amdgcn_mfma_f32_16x16x32_f16(aF[m], bF[n], acc[m][n], 0, 0, 0);
    cur ^= 1;
  }

  // ---- fused epilogue, m-sliced (proven r11/r12/r14, verbatim) ----
  __syncthreads();
  f16* sH = &sA[0][0];
  f16* sL = &sB[0][0];

  for (int j = 0; j < 4; ++j) {
    int u = t + j * 256;
    int r = u >> 3, c8 = (u & 7) * 8;
    *(h16x8*)&sH[r * 64 + c8] =
        *(const h16x8*)(hid + (size_t)(brow + r) * LRDIM + c8);
    const float* lp = L2 + (size_t)(bcol + r) * LRDIM + c8;
    *(h16x8*)&sL[r * 64 + c8] = pack8(((const float4*)lp)[0], ((const float4*)lp)[1]);
  }
  __syncthreads();

  float sc[4], bi[4];
#pragma unroll
  for (int n = 0; n < 4; ++n) {
    int o = bcol + wc * 64 + n * 16 + (l & 15);
    sc[n] = scale[o];
    bi[n] = bias[o];
  }

  // pass 1: mul = hid @ L2[0:4096]^T + scale ; acc <- mul * acc
  {
    h16x8 lB[4][2];
#pragma unroll
    for (int n = 0; n < 4; ++n)
#pragma unroll
      for (int kk = 0; kk < 2; ++kk)
        lB[n][kk] = *(const h16x8*)&sL[(wc * 64 + n * 16 + (l & 15)) * 64 + kk * 32 + (l >> 4) * 8];
#pragma unroll
    for (int m = 0; m < 4; ++m) {
      h16x8 hA0 = *(const h16x8*)&sH[(wr * 64 + m * 16 + (l & 15)) * 64 + (l >> 4) * 8];
      h16x8 hA1 = *(const h16x8*)&sH[(wr * 64 + m * 16 + (l & 15)) * 64 + 32 + (l >> 4) * 8];
      f32x4 mm[4];
#pragma unroll
      for (int n = 0; n < 4; ++n) {
        f32x4 mi = { sc[n], sc[n], sc[n], sc[n] };
        mm[n] = mi;
      }
#pragma unroll
      for (int n = 0; n < 4; ++n) {
        mm[n] = __builtin_amdgcn_mfma_f32_16x16x32_f16(hA0, lB[n][0], mm[n], 0, 0, 0);
        mm[n] = __builtin_amdgcn_mfma_f32_16x16x32_f16(hA1, lB[n][1], mm[n], 0, 0, 0);
      }
#pragma unroll
      for (int n = 0; n < 4; ++n)
        acc[m][n] *= mm[n];
    }
  }

  __syncthreads();
  for (int j = 0; j < 4; ++j) {
    int u = t + j * 256;
    int r = u >> 3, c8 = (u & 7) * 8;
    const float* lp = L2 + (size_t)(NDIM + bcol + r) * LRDIM + c8;
    *(h16x8*)&sL[r * 64 + c8] = pack8(((const float4*)lp)[0], ((const float4*)lp)[1]);
  }
  __syncthreads();

  // pass 2: add = hid @ L2[4096:8192]^T + bias ; out = add + acc
  {
    h16x8 lB[4][2];
#pragma unroll
    for (int n = 0; n < 4; ++n)
#pragma unroll
      for (int kk = 0; kk < 2; ++kk)
        lB[n][kk] = *(const h16x8*)&sL[(wc * 64 + n * 16 + (l & 15)) * 64 + kk * 32 + (l >> 4) * 8];
#pragma unroll
    for (int m = 0; m < 4; ++m) {
      h16x8 hA0 = *(const h16x8*)&sH[(wr * 64 + m * 16 + (l & 15)) * 64 + (l >> 4) * 8];
      h16x8 hA1 = *(const h16x8*)&sH[(wr * 64 + m * 16 + (l & 15)) * 64 + 32 + (l >> 4) * 8];
      f32x4 aa[4];
#pragma unroll
      for (int n = 0; n < 4; ++n) {
        f32x4 mi = { bi[n], bi[n], bi[n], bi[n] };
        aa[n] = mi;
      }
#pragma unroll
      for (int n = 0; n < 4; ++n) {
        aa[n] = __builtin_amdgcn_mfma_f32_16x16x32_f16(hA0, lB[n][0], aa[n], 0, 0, 0);
        aa[n] = __builtin_amdgcn_mfma_f32_16x16x32_f16(hA1, lB[n][1], aa[n], 0, 0, 0);
      }
      int rbase = brow + wr * 64 + m * 16 + ((l >> 4) << 2);
#pragma unroll
      for (int n = 0; n < 4; ++n) {
        int c = bcol + wc * 64 + n * 16 + (l & 15);
        f32x4 v = aa[n] + acc[m][n];
#pragma unroll
        for (int j = 0; j < 4; ++j)
          out[(size_t)(rbase + j) * NDIM + c] = v[j];
      }
    }
  }
}

// ---------------------------------------------------------------------------
extern "C" void kernel_launch(void* const* d_in, const int* in_sizes, int n_in,
                              void* d_out, int out_size, void* d_ws, size_t ws_size,
                              hipStream_t stream)
{
  const int SD[9] = {33554432,16777216,262144,524288,262144,262144,16777216,4096,4096};
  const int SA[9] = {4096,16777216,262144,262144,262144,524288,4096,16777216,33554432};
  bool dict = (n_in == 9), alph = (n_in == 9);
  if (n_in == 9) {
    for (int i = 0; i < 9; ++i) {
      if (in_sizes[i] != SD[i]) dict = false;
      if (in_sizes[i] != SA[i]) alph = false;
    }
  }
  if (!dict && !alph) {
    int ix = 0;
    for (int i = 0; i < n_in; ++i)
      if (in_sizes[i] == 33554432 || in_sizes[i] == 134217728) { ix = i; break; }
    dict = (ix == 0);
  }
  const float* x     = (const float*)d_in[dict ? 0 : 8];
  const void*  fr    =               d_in[1];
  const float* L1    = (const float*)d_in[dict ? 2 : 4];
  const float* L2    = (const float*)d_in[dict ? 3 : 5];
  const float* gs    = (const float*)d_in[dict ? 4 : 3];
  const float* gb    = (const float*)d_in[dict ? 5 : 2];
  const float* sa    = (const float*)d_in[dict ? 6 : 7];
  const float* scale = (const float*)d_in[dict ? 7 : 6];
  const float* bias  = (const float*)d_in[dict ? 8 : 0];
  float* out = (float*)d_out;

  const size_t MW_B = (size_t)NDIM * KDIM * 2;    // 33,554,432
  const size_t XH_B = (size_t)8192 * KDIM * 2;    // 67,108,864

  char* ws = (char*)d_ws;
  // ws_size proven >= this layout by rounds 9-15 (T2 path executed).
  f16* mW  = (f16*)ws;
  f16* xh  = (f16*)(ws + MW_B);
  f16* hid = (f16*)(ws + MW_B + XH_B);

  k9_cast_x<<<dim3(16384), dim3(256), 0, stream>>>(x, xh);
  k9_build_m<<<dim3(8192), dim3(256), 0, stream>>>(fr, gs, gb, sa, mW);
  k14_hid<<<dim3(256), dim3(256), 0, stream>>>(xh, L1, hid);
  k17_main<<<dim3(2048), dim3(256), 0, stream>>>(
      xh, mW, hid, L2, scale, bias, out);
}

// Round 17
// 445.408 us; speedup vs baseline: 1.3779x; 1.1269x over previous
//
#include <hip/hip_runtime.h>
#include <stdint.h>

typedef _Float16 f16;
typedef unsigned short u16;
typedef __attribute__((ext_vector_type(8))) _Float16 h16x8;
typedef __attribute__((ext_vector_type(8))) unsigned short u16x8;
typedef __attribute__((ext_vector_type(4))) float f32x4;

#define NDIM  4096
#define KDIM  4096
#define LRDIM 64
#define NTK   128        // KDIM / 32

#define MFMA16(a, b, c) __builtin_amdgcn_mfma_f32_16x16x32_f16((a), (b), (c), 0, 0, 0)

__device__ __forceinline__ float bf2f(u16 b) {
  union { unsigned u; float f; } c; c.u = ((unsigned)b) << 16; return c.f;
}
__device__ __forceinline__ float h2f(u16 b) {
  union { u16 u; f16 h; } c; c.u = b; return (float)c.h;
}
__device__ __forceinline__ h16x8 pack8(float4 a, float4 b) {
  h16x8 w = { (f16)a.x, (f16)a.y, (f16)a.z, (f16)a.w,
              (f16)b.x, (f16)b.y, (f16)b.z, (f16)b.w };
  return w;
}

// async global->LDS, 16B/lane; true addrspacecast (proven green r10-r16).
__device__ __forceinline__ void gll16(const void* g, void* l) {
  __builtin_amdgcn_global_load_lds(
      (const __attribute__((address_space(1))) void*)g,
      (__attribute__((address_space(3))) void*)l,
      16, 0, 0);
}

// ---------------------------------------------------------------------------
// frozen encoding classifier (proven): 0=f16, 1=bf16, 2=f32 halfword layout.
// ---------------------------------------------------------------------------
__device__ int frozen_mode(const void* frozen, int t) {
  const u16* fr = (const u16*)frozen;
  __shared__ int sE[256], sO[256];
  int ce = 0, co = 0;
  for (int j = 0; j < 8; ++j) {
    float ve = fabsf(bf2f(fr[t * 16 + 2 * j]));
    float vo = fabsf(bf2f(fr[t * 16 + 2 * j + 1]));
    if (ve >= 0.05f && ve <= 10.0f) ++ce;
    if (vo >= 0.05f && vo <= 10.0f) ++co;
  }
  sE[t] = ce; sO[t] = co;
  __syncthreads();
  for (int s = 128; s > 0; s >>= 1) {
    if (t < s) { sE[t] += sE[t + s]; sO[t] += sO[t + s]; }
    __syncthreads();
  }
  int te = sE[0], to = sO[0];
  __syncthreads();
  if (to > 1024) return (te > 1024) ? 1 : 2;
  return 0;
}

__device__ __forceinline__ h16x8 build_m8(
    const void* __restrict__ frozen, const float* __restrict__ gs,
    const float* __restrict__ gb, const float* __restrict__ sa,
    int o, int i0, int mode)
{
  size_t fo = (size_t)o * KDIM + i0;
  int gidx = (o >> 3) * 512 + (i0 >> 3);
  float gsf = gs[gidx], gbf = gb[gidx];
  float4 s0 = ((const float4*)(sa + fo))[0];
  float4 s1 = ((const float4*)(sa + fo))[1];
  float sv[8] = { s0.x, s0.y, s0.z, s0.w, s1.x, s1.y, s1.z, s1.w };
  float fv[8];
  if (mode == 2) {
    float4 q0 = ((const float4*)((const float*)frozen + fo))[0];
    float4 q1 = ((const float4*)((const float*)frozen + fo))[1];
    fv[0]=q0.x; fv[1]=q0.y; fv[2]=q0.z; fv[3]=q0.w;
    fv[4]=q1.x; fv[5]=q1.y; fv[6]=q1.z; fv[7]=q1.w;
  } else {
    u16x8 fb = *(const u16x8*)((const u16*)frozen + fo);
#pragma unroll
    for (int j = 0; j < 8; ++j) fv[j] = (mode == 1) ? bf2f(fb[j]) : h2f(fb[j]);
  }
  h16x8 w;
#pragma unroll
  for (int j = 0; j < 8; ++j) w[j] = (f16)(gbf + fv[j] * gsf + sv[j]);
  return w;
}

// ---------------------------------------------------------------------------
// prep kernels (proven, unchanged from r16)
// ---------------------------------------------------------------------------
__global__ __launch_bounds__(256) void k9_build_m(
    const void* __restrict__ frozen, const float* __restrict__ gs,
    const float* __restrict__ gb, const float* __restrict__ sa,
    f16* __restrict__ mW)
{
  int mode = frozen_mode(frozen, threadIdx.x);
  int idx = blockIdx.x * 256 + threadIdx.x;
  int o  = idx >> 9;
  int ig = idx & 511;
  h16x8 w = build_m8(frozen, gs, gb, sa, o, ig * 8, mode);
  *(h16x8*)(mW + (size_t)o * KDIM + ig * 8) = w;
}

__global__ __launch_bounds__(256) void k9_cast_x(const float* __restrict__ x,
                                                 f16* __restrict__ xh)
{
  size_t idx = (size_t)blockIdx.x * 256 + threadIdx.x;
  const float4* xp = (const float4*)x + idx * 2;
  *(h16x8*)(xh + idx * 8) = pack8(xp[0], xp[1]);
}

__global__ __launch_bounds__(256) void k14_hid(const f16* __restrict__ xh,
                                               const float* __restrict__ L1,
                                               f16* __restrict__ hid)
{
  __shared__ f16 sA[2][32 * 32];
  __shared__ f16 sB[2][64 * 32];
  int t = threadIdx.x;
  int l = t & 63, wid = t >> 6;
  int wr = wid >> 1, wc = wid & 1;
  int brow = blockIdx.x * 32;
  int ar = t >> 2, ac8 = (t & 3) * 8;
  int brw = t >> 2, bc8 = (t & 3) * 8;

  f32x4 acc[2] = {};

  {
    if (t < 128)
      gll16(xh + (size_t)(brow + ar) * KDIM + ac8, &sA[0][ar * 32 + ac8]);
    const float* lp = L1 + (size_t)brw * KDIM + bc8;
    *(h16x8*)&sB[0][brw * 32 + bc8] = pack8(((const float4*)lp)[0], ((const float4*)lp)[1]);
  }

  int cur = 0;
  const int NT = KDIM / 32;
  for (int kt = 0; kt < NT; ++kt) {
    __syncthreads();
    bool pf = (kt + 1 < NT);
    h16x8 wb;
    if (pf) {
      int k0 = (kt + 1) * 32;
      if (t < 128)
        gll16(xh + (size_t)(brow + ar) * KDIM + k0 + ac8, &sA[cur ^ 1][ar * 32 + ac8]);
      const float* lp = L1 + (size_t)brw * KDIM + k0 + bc8;
      wb = pack8(((const float4*)lp)[0], ((const float4*)lp)[1]);
    }
    h16x8 aF, bF[2];
    aF = *(const h16x8*)&sA[cur][(wr * 16 + (l & 15)) * 32 + (l >> 4) * 8];
#pragma unroll
    for (int n = 0; n < 2; ++n)
      bF[n] = *(const h16x8*)&sB[cur][(wc * 32 + n * 16 + (l & 15)) * 32 + (l >> 4) * 8];
#pragma unroll
    for (int n = 0; n < 2; ++n)
      acc[n] = MFMA16(aF, bF[n], acc[n]);
    if (pf)
      *(h16x8*)&sB[cur ^ 1][brw * 32 + bc8] = wb;
    cur ^= 1;
  }

#pragma unroll
  for (int n = 0; n < 2; ++n)
#pragma unroll
    for (int j = 0; j < 4; ++j) {
      int r = wr * 16 + ((l >> 4) << 2) + j;
      int c = wc * 32 + n * 16 + (l & 15);
      hid[(size_t)(brow + r) * LRDIM + c] = (f16)acc[n][j];
    }
}

// ---------------------------------------------------------------------------
// k18_main: 256x256 tile, BK=32, 512 threads (8 waves, 2M x 4N), 3 K-tile
// LDS buffers (96KB), stage-2-ahead with counted vmcnt(4) (never 0 in steady
// state), 4 phases/K-tile each {ds_read | stage | barrier | setprio MFMA |
// barrier}. Hazards closed:
//   W-after-R: stage of tile t+2 -> buf[(t+2)%3] = buf[(t-1)%3]; tile t-1's
//     reads end before tile t's first barrier; stages issue after it.
//   Residency: vmcnt(4) at tile t's last phase leaves only tile t+2's 4
//     loads outstanding => tile t+1 fully landed before its reads.
//     Tail (kt >= NTK-2): vmcnt(0).
// Epilogue: hid + both L2 halves staged simultaneously (96KB), fused
// mul/add via K=64 MFMA (proven fragment formulas, wm/wn-widened).
// ---------------------------------------------------------------------------
__global__ __launch_bounds__(512) void k18_main(
    const f16* __restrict__ xh, const f16* __restrict__ mW,
    const f16* __restrict__ hid, const float* __restrict__ L2,
    const float* __restrict__ scale, const float* __restrict__ bias,
    float* __restrict__ out)
{
  __shared__ f16 lds[3][16384];     // 3 x (A[256][32] + B[256][32]) = 96 KB

  int t = threadIdx.x;              // 0..511
  int l = t & 63, wid = t >> 6;     // 8 waves
  int wm = wid >> 2, wn = wid & 3;  // wave tile: rows wm*128..+128, cols wn*64..+64

  // XCD 2-D chunked mapping: 512 blocks = 8 XCDs x 64 (proven r16 pattern)
  int wg = blockIdx.x;
  int xcd = wg & 7, w = wg >> 3;
  int bm = xcd * 4 + (w & 3);       // 0..31
  int bn = w >> 2;                  // 0..15
  int brow = bm * 256, bcol = bn * 256;

  // stage unit-quarter q of K-tile kt2 into buffer buf (1 gll16/thread)
  auto stage = [&](int q, int kt2, int buf) {
    int u = q * 512 + t;            // 0..2047 across 4 phases
    if (u < 1024) {                 // A: [256][32], unit u -> row u>>2, col8 (u&3)*8
      gll16(xh + (size_t)(brow + (u >> 2)) * KDIM + kt2 * 32 + (u & 3) * 8,
            &lds[buf][u * 8]);
    } else {                        // B
      int v = u - 1024;
      gll16(mW + (size_t)(bcol + (v >> 2)) * KDIM + kt2 * 32 + (v & 3) * 8,
            &lds[buf][8192 + v * 8]);
    }
  };

  // ---- prologue: stage K-tiles 0 (buf0) and 1 (buf1); gate tile 0 ----
#pragma unroll
  for (int q = 0; q < 4; ++q) stage(q, 0, 0);
#pragma unroll
  for (int q = 0; q < 4; ++q) stage(q, 1, 1);
  asm volatile("s_waitcnt vmcnt(4)" ::: "memory");   // tile 0 landed
  __builtin_amdgcn_sched_barrier(0);
  __builtin_amdgcn_s_barrier();

  f32x4 acc[8][4] = {};

  for (int kt = 0; kt < NTK; ++kt) {
    const f16* A = &lds[kt % 3][0];
    const f16* B = &lds[kt % 3][8192];
    int sb = (kt + 2) % 3;
    bool st = (kt + 2) < NTK;
    int k2 = kt + 2;

    int ar0 = (wm * 128 + (l & 15)) * 32 + (l >> 4) * 8;  // +512/el per m-frag
    int br0 = (wn * 64  + (l & 15)) * 32 + (l >> 4) * 8;  // +512/el per n-frag

    h16x8 aF[4], bF[4];

    // ---------- phase 0: aF f0-3 + bF n0-1 | stage q0 | mfma m0-3 x n0-1
#pragma unroll
    for (int f = 0; f < 4; ++f) aF[f] = *(const h16x8*)&A[ar0 + f * 512];
    bF[0] = *(const h16x8*)&B[br0];
    bF[1] = *(const h16x8*)&B[br0 + 512];
    if (st) stage(0, k2, sb);
    __builtin_amdgcn_s_barrier();
    __builtin_amdgcn_s_setprio(1);
#pragma unroll
    for (int f = 0; f < 4; ++f) {
      acc[f][0] = MFMA16(aF[f], bF[0], acc[f][0]);
      acc[f][1] = MFMA16(aF[f], bF[1], acc[f][1]);
    }
    __builtin_amdgcn_s_setprio(0);
    __builtin_amdgcn_s_barrier();

    // ---------- phase 1: bF n2-3 | stage q1 | mfma m0-3 x n2-3
    bF[2] = *(const h16x8*)&B[br0 + 1024];
    bF[3] = *(const h16x8*)&B[br0 + 1536];
    if (st) stage(1, k2, sb);
    __builtin_amdgcn_s_barrier();
    __builtin_amdgcn_s_setprio(1);
#pragma unroll
    for (int f = 0; f < 4; ++f) {
      acc[f][2] = MFMA16(aF[f], bF[2], acc[f][2]);
      acc[f][3] = MFMA16(aF[f], bF[3], acc[f][3]);
    }
    __builtin_amdgcn_s_setprio(0);
    __builtin_amdgcn_s_barrier();

    // ---------- phase 2: aF f4-7 | stage q2 | mfma m4-7 x n0-1
#pragma unroll
    for (int f = 0; f < 4; ++f) aF[f] = *(const h16x8*)&A[ar0 + (f + 4) * 512];
    if (st) stage(2, k2, sb);
    __builtin_amdgcn_s_barrier();
    __builtin_amdgcn_s_setprio(1);
#pragma unroll
    for (int f = 0; f < 4; ++f) {
      acc[f + 4][0] = MFMA16(aF[f], bF[0], acc[f + 4][0]);
      acc[f + 4][1] = MFMA16(aF[f], bF[1], acc[f + 4][1]);
    }
    __builtin_amdgcn_s_setprio(0);
    __builtin_amdgcn_s_barrier();

    // ---------- phase 3: stage q3 | vmcnt gate | mfma m4-7 x n2-3
    if (st) stage(3, k2, sb);
    if (kt < NTK - 2) {
      asm volatile("s_waitcnt vmcnt(4)" ::: "memory");  // tile kt+1 resident
    } else {
      asm volatile("s_waitcnt vmcnt(0)" ::: "memory");  // tail drain
    }
    __builtin_amdgcn_sched_barrier(0);
    __builtin_amdgcn_s_barrier();
    __builtin_amdgcn_s_setprio(1);
#pragma unroll
    for (int f = 0; f < 4; ++f) {
      acc[f + 4][2] = MFMA16(aF[f], bF[2], acc[f + 4][2]);
      acc[f + 4][3] = MFMA16(aF[f], bF[3], acc[f + 4][3]);
    }
    __builtin_amdgcn_s_setprio(0);
    __builtin_amdgcn_s_barrier();
  }

  // ---- fused epilogue: stage hid + both L2 halves (96KB), then mul/add ----
  f16* sH  = &lds[0][0];            // [256][64] hid tile
  f16* sLm = &lds[1][0];            // [256][64] L2 mul half (f16)
  f16* sLa = &lds[2][0];            // [256][64] L2 add half (f16)

#pragma unroll
  for (int q = 0; q < 4; ++q) {     // sH via gll16: 2048 units
    int u = q * 512 + t;
    gll16(hid + (size_t)(brow + (u >> 3)) * LRDIM + (u & 7) * 8, &sH[u * 8]);
  }
#pragma unroll
  for (int q = 0; q < 4; ++q) {     // sLm reg-staged from f32 L2
    int u = q * 512 + t;
    const float* lp = L2 + (size_t)(bcol + (u >> 3)) * LRDIM + (u & 7) * 8;
    *(h16x8*)&sLm[u * 8] = pack8(((const float4*)lp)[0], ((const float4*)lp)[1]);
  }
#pragma unroll
  for (int q = 0; q < 4; ++q) {     // sLa
    int u = q * 512 + t;
    const float* lp = L2 + (size_t)(NDIM + bcol + (u >> 3)) * LRDIM + (u & 7) * 8;
    *(h16x8*)&sLa[u * 8] = pack8(((const float4*)lp)[0], ((const float4*)lp)[1]);
  }
  __syncthreads();                  // full drain (vmcnt+lgkm) before reads

  float sc[4], bi[4];
#pragma unroll
  for (int n = 0; n < 4; ++n) {
    int o = bcol + wn * 64 + n * 16 + (l & 15);
    sc[n] = scale[o];
    bi[n] = bias[o];
  }

  // pass 1: mul = hid @ L2[0:4096]^T + scale ; acc <- mul * acc
  {
    h16x8 lB[4][2];
#pragma unroll
    for (int n = 0; n < 4; ++n)
#pragma unroll
      for (int kk = 0; kk < 2; ++kk)
        lB[n][kk] = *(const h16x8*)&sLm[(wn * 64 + n * 16 + (l & 15)) * 64 + kk * 32 + (l >> 4) * 8];
#pragma unroll
    for (int f = 0; f < 8; ++f) {
      h16x8 h0 = *(const h16x8*)&sH[(wm * 128 + f * 16 + (l & 15)) * 64 + (l >> 4) * 8];
      h16x8 h1 = *(const h16x8*)&sH[(wm * 128 + f * 16 + (l & 15)) * 64 + 32 + (l >> 4) * 8];
      f32x4 mm[4];
#pragma unroll
      for (int n = 0; n < 4; ++n) {
        f32x4 mi = { sc[n], sc[n], sc[n], sc[n] };
        mm[n] = mi;
      }
#pragma unroll
      for (int n = 0; n < 4; ++n) {
        mm[n] = MFMA16(h0, lB[n][0], mm[n]);
        mm[n] = MFMA16(h1, lB[n][1], mm[n]);
      }
#pragma unroll
      for (int n = 0; n < 4; ++n)
        acc[f][n] *= mm[n];
    }
  }

  // pass 2: add = hid @ L2[4096:8192]^T + bias ; out = add + acc
  {
    h16x8 lB[4][2];
#pragma unroll
    for (int n = 0; n < 4; ++n)
#pragma unroll
      for (int kk = 0; kk < 2; ++kk)
        lB[n][kk] = *(const h16x8*)&sLa[(wn * 64 + n * 16 + (l & 15)) * 64 + kk * 32 + (l >> 4) * 8];
#pragma unroll
    for (int f = 0; f < 8; ++f) {
      h16x8 h0 = *(const h16x8*)&sH[(wm * 128 + f * 16 + (l & 15)) * 64 + (l >> 4) * 8];
      h16x8 h1 = *(const h16x8*)&sH[(wm * 128 + f * 16 + (l & 15)) * 64 + 32 + (l >> 4) * 8];
      f32x4 aa[4];
#pragma unroll
      for (int n = 0; n < 4; ++n) {
        f32x4 mi = { bi[n], bi[n], bi[n], bi[n] };
        aa[n] = mi;
      }
#pragma unroll
      for (int n = 0; n < 4; ++n) {
        aa[n] = MFMA16(h0, lB[n][0], aa[n]);
        aa[n] = MFMA16(h1, lB[n][1], aa[n]);
      }
      int rbase = brow + wm * 128 + f * 16 + ((l >> 4) << 2);
#pragma unroll
      for (int n = 0; n < 4; ++n) {
        int c = bcol + wn * 64 + n * 16 + (l & 15);
        f32x4 v = aa[n] + acc[f][n];
#pragma unroll
        for (int j = 0; j < 4; ++j)
          out[(size_t)(rbase + j) * NDIM + c] = v[j];
      }
    }
  }
}

// ---------------------------------------------------------------------------
extern "C" void kernel_launch(void* const* d_in, const int* in_sizes, int n_in,
                              void* d_out, int out_size, void* d_ws, size_t ws_size,
                              hipStream_t stream)
{
  const int SD[9] = {33554432,16777216,262144,524288,262144,262144,16777216,4096,4096};
  const int SA[9] = {4096,16777216,262144,262144,262144,524288,4096,16777216,33554432};
  bool dict = (n_in == 9), alph = (n_in == 9);
  if (n_in == 9) {
    for (int i = 0; i < 9; ++i) {
      if (in_sizes[i] != SD[i]) dict = false;
      if (in_sizes[i] != SA[i]) alph = false;
    }
  }
  if (!dict && !alph) {
    int ix = 0;
    for (int i = 0; i < n_in; ++i)
      if (in_sizes[i] == 33554432 || in_sizes[i] == 134217728) { ix = i; break; }
    dict = (ix == 0);
  }
  const float* x     = (const float*)d_in[dict ? 0 : 8];
  const void*  fr    =               d_in[1];
  const float* L1    = (const float*)d_in[dict ? 2 : 4];
  const float* L2    = (const float*)d_in[dict ? 3 : 5];
  const float* gs    = (const float*)d_in[dict ? 4 : 3];
  const float* gb    = (const float*)d_in[dict ? 5 : 2];
  const float* sa    = (const float*)d_in[dict ? 6 : 7];
  const float* scale = (const float*)d_in[dict ? 7 : 6];
  const float* bias  = (const float*)d_in[dict ? 8 : 0];
  float* out = (float*)d_out;

  const size_t MW_B = (size_t)NDIM * KDIM * 2;    // 33,554,432
  const size_t XH_B = (size_t)8192 * KDIM * 2;    // 67,108,864

  char* ws = (char*)d_ws;
  // ws_size proven >= this layout by rounds 9-16 (T2 path executed).
  f16* mW  = (f16*)ws;
  f16* xh  = (f16*)(ws + MW_B);
  f16* hid = (f16*)(ws + MW_B + XH_B);

  k9_cast_x<<<dim3(16384), dim3(256), 0, stream>>>(x, xh);
  k9_build_m<<<dim3(8192), dim3(256), 0, stream>>>(fr, gs, gb, sa, mW);
  k14_hid<<<dim3(256), dim3(256), 0, stream>>>(xh, L1, hid);
  k18_main<<<dim3(512), dim3(512), 0, stream>>>(
      xh, mW, hid, L2, scale, bias, out);
}

// Round 18
// 425.399 us; speedup vs baseline: 1.4427x; 1.0470x over previous
//
#include <hip/hip_runtime.h>
#include <stdint.h>

typedef _Float16 f16;
typedef unsigned short u16;
typedef __attribute__((ext_vector_type(8))) _Float16 h16x8;
typedef __attribute__((ext_vector_type(8))) unsigned short u16x8;
typedef __attribute__((ext_vector_type(4))) float f32x4;

#define NDIM  4096
#define KDIM  4096
#define LRDIM 64
#define NTK   128        // KDIM / 32

#define MFMA16(a, b, c) __builtin_amdgcn_mfma_f32_16x16x32_f16((a), (b), (c), 0, 0, 0)

__device__ __forceinline__ float bf2f(u16 b) {
  union { unsigned u; float f; } c; c.u = ((unsigned)b) << 16; return c.f;
}
__device__ __forceinline__ float h2f(u16 b) {
  union { u16 u; f16 h; } c; c.u = b; return (float)c.h;
}
__device__ __forceinline__ h16x8 pack8(float4 a, float4 b) {
  h16x8 w = { (f16)a.x, (f16)a.y, (f16)a.z, (f16)a.w,
              (f16)b.x, (f16)b.y, (f16)b.z, (f16)b.w };
  return w;
}

// async global->LDS, 16B/lane; true addrspacecast (proven green r10-r17).
__device__ __forceinline__ void gll16(const void* g, void* l) {
  __builtin_amdgcn_global_load_lds(
      (const __attribute__((address_space(1))) void*)g,
      (__attribute__((address_space(3))) void*)l,
      16, 0, 0);
}

// ---------------------------------------------------------------------------
// frozen encoding classifier (proven): 0=f16, 1=bf16, 2=f32 halfword layout.
// ---------------------------------------------------------------------------
__device__ int frozen_mode(const void* frozen, int t) {
  const u16* fr = (const u16*)frozen;
  __shared__ int sE[256], sO[256];
  int ce = 0, co = 0;
  for (int j = 0; j < 8; ++j) {
    float ve = fabsf(bf2f(fr[t * 16 + 2 * j]));
    float vo = fabsf(bf2f(fr[t * 16 + 2 * j + 1]));
    if (ve >= 0.05f && ve <= 10.0f) ++ce;
    if (vo >= 0.05f && vo <= 10.0f) ++co;
  }
  sE[t] = ce; sO[t] = co;
  __syncthreads();
  for (int s = 128; s > 0; s >>= 1) {
    if (t < s) { sE[t] += sE[t + s]; sO[t] += sO[t + s]; }
    __syncthreads();
  }
  int te = sE[0], to = sO[0];
  __syncthreads();
  if (to > 1024) return (te > 1024) ? 1 : 2;
  return 0;
}

__device__ __forceinline__ h16x8 build_m8(
    const void* __restrict__ frozen, const float* __restrict__ gs,
    const float* __restrict__ gb, const float* __restrict__ sa,
    int o, int i0, int mode)
{
  size_t fo = (size_t)o * KDIM + i0;
  int gidx = (o >> 3) * 512 + (i0 >> 3);
  float gsf = gs[gidx], gbf = gb[gidx];
  float4 s0 = ((const float4*)(sa + fo))[0];
  float4 s1 = ((const float4*)(sa + fo))[1];
  float sv[8] = { s0.x, s0.y, s0.z, s0.w, s1.x, s1.y, s1.z, s1.w };
  float fv[8];
  if (mode == 2) {
    float4 q0 = ((const float4*)((const float*)frozen + fo))[0];
    float4 q1 = ((const float4*)((const float*)frozen + fo))[1];
    fv[0]=q0.x; fv[1]=q0.y; fv[2]=q0.z; fv[3]=q0.w;
    fv[4]=q1.x; fv[5]=q1.y; fv[6]=q1.z; fv[7]=q1.w;
  } else {
    u16x8 fb = *(const u16x8*)((const u16*)frozen + fo);
#pragma unroll
    for (int j = 0; j < 8; ++j) fv[j] = (mode == 1) ? bf2f(fb[j]) : h2f(fb[j]);
  }
  h16x8 w;
#pragma unroll
  for (int j = 0; j < 8; ++j) w[j] = (f16)(gbf + fv[j] * gsf + sv[j]);
  return w;
}

// ---------------------------------------------------------------------------
// prep kernels (proven, unchanged)
// ---------------------------------------------------------------------------
__global__ __launch_bounds__(256) void k9_build_m(
    const void* __restrict__ frozen, const float* __restrict__ gs,
    const float* __restrict__ gb, const float* __restrict__ sa,
    f16* __restrict__ mW)
{
  int mode = frozen_mode(frozen, threadIdx.x);
  int idx = blockIdx.x * 256 + threadIdx.x;
  int o  = idx >> 9;
  int ig = idx & 511;
  h16x8 w = build_m8(frozen, gs, gb, sa, o, ig * 8, mode);
  *(h16x8*)(mW + (size_t)o * KDIM + ig * 8) = w;
}

__global__ __launch_bounds__(256) void k9_cast_x(const float* __restrict__ x,
                                                 f16* __restrict__ xh)
{
  size_t idx = (size_t)blockIdx.x * 256 + threadIdx.x;
  const float4* xp = (const float4*)x + idx * 2;
  *(h16x8*)(xh + idx * 8) = pack8(xp[0], xp[1]);
}

__global__ __launch_bounds__(256) void k14_hid(const f16* __restrict__ xh,
                                               const float* __restrict__ L1,
                                               f16* __restrict__ hid)
{
  __shared__ f16 sA[2][32 * 32];
  __shared__ f16 sB[2][64 * 32];
  int t = threadIdx.x;
  int l = t & 63, wid = t >> 6;
  int wr = wid >> 1, wc = wid & 1;
  int brow = blockIdx.x * 32;
  int ar = t >> 2, ac8 = (t & 3) * 8;
  int brw = t >> 2, bc8 = (t & 3) * 8;

  f32x4 acc[2] = {};

  {
    if (t < 128)
      gll16(xh + (size_t)(brow + ar) * KDIM + ac8, &sA[0][ar * 32 + ac8]);
    const float* lp = L1 + (size_t)brw * KDIM + bc8;
    *(h16x8*)&sB[0][brw * 32 + bc8] = pack8(((const float4*)lp)[0], ((const float4*)lp)[1]);
  }

  int cur = 0;
  const int NT = KDIM / 32;
  for (int kt = 0; kt < NT; ++kt) {
    __syncthreads();
    bool pf = (kt + 1 < NT);
    h16x8 wb;
    if (pf) {
      int k0 = (kt + 1) * 32;
      if (t < 128)
        gll16(xh + (size_t)(brow + ar) * KDIM + k0 + ac8, &sA[cur ^ 1][ar * 32 + ac8]);
      const float* lp = L1 + (size_t)brw * KDIM + k0 + bc8;
      wb = pack8(((const float4*)lp)[0], ((const float4*)lp)[1]);
    }
    h16x8 aF, bF[2];
    aF = *(const h16x8*)&sA[cur][(wr * 16 + (l & 15)) * 32 + (l >> 4) * 8];
#pragma unroll
    for (int n = 0; n < 2; ++n)
      bF[n] = *(const h16x8*)&sB[cur][(wc * 32 + n * 16 + (l & 15)) * 32 + (l >> 4) * 8];
#pragma unroll
    for (int n = 0; n < 2; ++n)
      acc[n] = MFMA16(aF, bF[n], acc[n]);
    if (pf)
      *(h16x8*)&sB[cur ^ 1][brw * 32 + bc8] = wb;
    cur ^= 1;
  }

#pragma unroll
  for (int n = 0; n < 2; ++n)
#pragma unroll
    for (int j = 0; j < 4; ++j) {
      int r = wr * 16 + ((l >> 4) << 2) + j;
      int c = wc * 32 + n * 16 + (l & 15);
      hid[(size_t)(brow + r) * LRDIM + c] = (f16)acc[n][j];
    }
}

// ---------------------------------------------------------------------------
// k18b_main: r17's proven 8-phase kernel + K-loop LDS bank-conflict swizzle
// (rule #21: linear LDS dest, pre-permuted GLOBAL source, same involution on
// the read). s' = s ^ ((row>>1)&3): start banks spread over all 8 positions
// per 8 rows -> 2 lanes/bank (free) vs 8-way before. Read XOR is
// lane-constant (fragment row bases are multiples of 16). vmcnt schedule,
// barriers, epilogue: byte-identical to r17.
// ---------------------------------------------------------------------------
__global__ __launch_bounds__(512) void k18b_main(
    const f16* __restrict__ xh, const f16* __restrict__ mW,
    const f16* __restrict__ hid, const float* __restrict__ L2,
    const float* __restrict__ scale, const float* __restrict__ bias,
    float* __restrict__ out)
{
  __shared__ f16 lds[3][16384];     // 3 x (A[256][32] + B[256][32]) = 96 KB

  int t = threadIdx.x;              // 0..511
  int l = t & 63, wid = t >> 6;     // 8 waves
  int wm = wid >> 2, wn = wid & 3;  // wave tile: rows wm*128..+128, cols wn*64..+64

  // XCD 2-D chunked mapping (proven r16): 512 blocks = 8 XCDs x 64
  int wg = blockIdx.x;
  int xcd = wg & 7, w = wg >> 3;
  int bm = xcd * 4 + (w & 3);       // 0..31
  int bn = w >> 2;                  // 0..15
  int brow = bm * 256, bcol = bn * 256;

  // stage unit-quarter q of K-tile kt2 into buffer buf (1 gll16/thread).
  // Source-side swizzle: LDS unit (r, s_lds) receives global slot
  // s_g = s_lds ^ ((r>>1)&3)  [r = u>>2 => (r>>1)&3 = (u>>3)&3].
  auto stage = [&](int q, int kt2, int buf) {
    int u = q * 512 + t;            // 0..2047 across 4 phases
    if (u < 1024) {                 // A: [256][32]
      int sg = (u & 3) ^ ((u >> 3) & 3);
      gll16(xh + (size_t)(brow + (u >> 2)) * KDIM + kt2 * 32 + sg * 8,
            &lds[buf][u * 8]);
    } else {                        // B
      int v = u - 1024;
      int sg = (v & 3) ^ ((v >> 3) & 3);
      gll16(mW + (size_t)(bcol + (v >> 2)) * KDIM + kt2 * 32 + sg * 8,
            &lds[buf][8192 + v * 8]);
    }
  };

  // ---- prologue: stage K-tiles 0 (buf0) and 1 (buf1); gate tile 0 ----
#pragma unroll
  for (int q = 0; q < 4; ++q) stage(q, 0, 0);
#pragma unroll
  for (int q = 0; q < 4; ++q) stage(q, 1, 1);
  asm volatile("s_waitcnt vmcnt(4)" ::: "memory");   // tile 0 landed
  __builtin_amdgcn_sched_barrier(0);
  __builtin_amdgcn_s_barrier();

  f32x4 acc[8][4] = {};

  // read-side swizzle: global slot (l>>4) of row r lives at LDS slot
  // (l>>4) ^ ((r>>1)&3); with r = base16 + (l&15), that's (l>>4)^((l>>1)&3).
  int X = ((l >> 4) ^ ((l >> 1) & 3)) * 8;

  for (int kt = 0; kt < NTK; ++kt) {
    const f16* A = &lds[kt % 3][0];
    const f16* B = &lds[kt % 3][8192];
    int sb = (kt + 2) % 3;
    bool st = (kt + 2) < NTK;
    int k2 = kt + 2;

    int ar0 = (wm * 128 + (l & 15)) * 32 + X;  // +512/el per m-frag
    int br0 = (wn * 64  + (l & 15)) * 32 + X;  // +512/el per n-frag

    h16x8 aF[4], bF[4];

    // ---------- phase 0: aF f0-3 + bF n0-1 | stage q0 | mfma m0-3 x n0-1
#pragma unroll
    for (int f = 0; f < 4; ++f) aF[f] = *(const h16x8*)&A[ar0 + f * 512];
    bF[0] = *(const h16x8*)&B[br0];
    bF[1] = *(const h16x8*)&B[br0 + 512];
    if (st) stage(0, k2, sb);
    __builtin_amdgcn_s_barrier();
    __builtin_amdgcn_s_setprio(1);
#pragma unroll
    for (int f = 0; f < 4; ++f) {
      acc[f][0] = MFMA16(aF[f], bF[0], acc[f][0]);
      acc[f][1] = MFMA16(aF[f], bF[1], acc[f][1]);
    }
    __builtin_amdgcn_s_setprio(0);
    __builtin_amdgcn_s_barrier();

    // ---------- phase 1: bF n2-3 | stage q1 | mfma m0-3 x n2-3
    bF[2] = *(const h16x8*)&B[br0 + 1024];
    bF[3] = *(const h16x8*)&B[br0 + 1536];
    if (st) stage(1, k2, sb);
    __builtin_amdgcn_s_barrier();
    __builtin_amdgcn_s_setprio(1);
#pragma unroll
    for (int f = 0; f < 4; ++f) {
      acc[f][2] = MFMA16(aF[f], bF[2], acc[f][2]);
      acc[f][3] = MFMA16(aF[f], bF[3], acc[f][3]);
    }
    __builtin_amdgcn_s_setprio(0);
    __builtin_amdgcn_s_barrier();

    // ---------- phase 2: aF f4-7 | stage q2 | mfma m4-7 x n0-1
#pragma unroll
    for (int f = 0; f < 4; ++f) aF[f] = *(const h16x8*)&A[ar0 + (f + 4) * 512];
    if (st) stage(2, k2, sb);
    __builtin_amdgcn_s_barrier();
    __builtin_amdgcn_s_setprio(1);
#pragma unroll
    for (int f = 0; f < 4; ++f) {
      acc[f + 4][0] = MFMA16(aF[f], bF[0], acc[f + 4][0]);
      acc[f + 4][1] = MFMA16(aF[f], bF[1], acc[f + 4][1]);
    }
    __builtin_amdgcn_s_setprio(0);
    __builtin_amdgcn_s_barrier();

    // ---------- phase 3: stage q3 | vmcnt gate | mfma m4-7 x n2-3
    if (st) stage(3, k2, sb);
    if (kt < NTK - 2) {
      asm volatile("s_waitcnt vmcnt(4)" ::: "memory");  // tile kt+1 resident
    } else {
      asm volatile("s_waitcnt vmcnt(0)" ::: "memory");  // tail drain
    }
    __builtin_amdgcn_sched_barrier(0);
    __builtin_amdgcn_s_barrier();
    __builtin_amdgcn_s_setprio(1);
#pragma unroll
    for (int f = 0; f < 4; ++f) {
      acc[f + 4][2] = MFMA16(aF[f], bF[2], acc[f + 4][2]);
      acc[f + 4][3] = MFMA16(aF[f], bF[3], acc[f + 4][3]);
    }
    __builtin_amdgcn_s_setprio(0);
    __builtin_amdgcn_s_barrier();
  }

  // ---- fused epilogue (byte-identical to r17) ----
  f16* sH  = &lds[0][0];            // [256][64] hid tile
  f16* sLm = &lds[1][0];            // [256][64] L2 mul half (f16)
  f16* sLa = &lds[2][0];            // [256][64] L2 add half (f16)

#pragma unroll
  for (int q = 0; q < 4; ++q) {     // sH via gll16: 2048 units
    int u = q * 512 + t;
    gll16(hid + (size_t)(brow + (u >> 3)) * LRDIM + (u & 7) * 8, &sH[u * 8]);
  }
#pragma unroll
  for (int q = 0; q < 4; ++q) {     // sLm reg-staged from f32 L2
    int u = q * 512 + t;
    const float* lp = L2 + (size_t)(bcol + (u >> 3)) * LRDIM + (u & 7) * 8;
    *(h16x8*)&sLm[u * 8] = pack8(((const float4*)lp)[0], ((const float4*)lp)[1]);
  }
#pragma unroll
  for (int q = 0; q < 4; ++q) {     // sLa
    int u = q * 512 + t;
    const float* lp = L2 + (size_t)(NDIM + bcol + (u >> 3)) * LRDIM + (u & 7) * 8;
    *(h16x8*)&sLa[u * 8] = pack8(((const float4*)lp)[0], ((const float4*)lp)[1]);
  }
  __syncthreads();                  // full drain (vmcnt+lgkm) before reads

  float sc[4], bi[4];
#pragma unroll
  for (int n = 0; n < 4; ++n) {
    int o = bcol + wn * 64 + n * 16 + (l & 15);
    sc[n] = scale[o];
    bi[n] = bias[o];
  }

  // pass 1: mul = hid @ L2[0:4096]^T + scale ; acc <- mul * acc
  {
    h16x8 lB[4][2];
#pragma unroll
    for (int n = 0; n < 4; ++n)
#pragma unroll
      for (int kk = 0; kk < 2; ++kk)
        lB[n][kk] = *(const h16x8*)&sLm[(wn * 64 + n * 16 + (l & 15)) * 64 + kk * 32 + (l >> 4) * 8];
#pragma unroll
    for (int f = 0; f < 8; ++f) {
      h16x8 h0 = *(const h16x8*)&sH[(wm * 128 + f * 16 + (l & 15)) * 64 + (l >> 4) * 8];
      h16x8 h1 = *(const h16x8*)&sH[(wm * 128 + f * 16 + (l & 15)) * 64 + 32 + (l >> 4) * 8];
      f32x4 mm[4];
#pragma unroll
      for (int n = 0; n < 4; ++n) {
        f32x4 mi = { sc[n], sc[n], sc[n], sc[n] };
        mm[n] = mi;
      }
#pragma unroll
      for (int n = 0; n < 4; ++n) {
        mm[n] = MFMA16(h0, lB[n][0], mm[n]);
        mm[n] = MFMA16(h1, lB[n][1], mm[n]);
      }
#pragma unroll
      for (int n = 0; n < 4; ++n)
        acc[f][n] *= mm[n];
    }
  }

  // pass 2: add = hid @ L2[4096:8192]^T + bias ; out = add + acc
  {
    h16x8 lB[4][2];
#pragma unroll
    for (int n = 0; n < 4; ++n)
#pragma unroll
      for (int kk = 0; kk < 2; ++kk)
        lB[n][kk] = *(const h16x8*)&sLa[(wn * 64 + n * 16 + (l & 15)) * 64 + kk * 32 + (l >> 4) * 8];
#pragma unroll
    for (int f = 0; f < 8; ++f) {
      h16x8 h0 = *(const h16x8*)&sH[(wm * 128 + f * 16 + (l & 15)) * 64 + (l >> 4) * 8];
      h16x8 h1 = *(const h16x8*)&sH[(wm * 128 + f * 16 + (l & 15)) * 64 + 32 + (l >> 4) * 8];
      f32x4 aa[4];
#pragma unroll
      for (int n = 0; n < 4; ++n) {
        f32x4 mi = { bi[n], bi[n], bi[n], bi[n] };
        aa[n] = mi;
      }
#pragma unroll
      for (int n = 0; n < 4; ++n) {
        aa[n] = MFMA16(h0, lB[n][0], aa[n]);
        aa[n] = MFMA16(h1, lB[n][1], aa[n]);
      }
      int rbase = brow + wm * 128 + f * 16 + ((l >> 4) << 2);
#pragma unroll
      for (int n = 0; n < 4; ++n) {
        int c = bcol + wn * 64 + n * 16 + (l & 15);
        f32x4 v = aa[n] + acc[f][n];
#pragma unroll
        for (int j = 0; j < 4; ++j)
          out[(size_t)(rbase + j) * NDIM + c] = v[j];
      }
    }
  }
}

// ---------------------------------------------------------------------------
extern "C" void kernel_launch(void* const* d_in, const int* in_sizes, int n_in,
                              void* d_out, int out_size, void* d_ws, size_t ws_size,
                              hipStream_t stream)
{
  const int SD[9] = {33554432,16777216,262144,524288,262144,262144,16777216,4096,4096};
  const int SA[9] = {4096,16777216,262144,262144,262144,524288,4096,16777216,33554432};
  bool dict = (n_in == 9), alph = (n_in == 9);
  if (n_in == 9) {
    for (int i = 0; i < 9; ++i) {
      if (in_sizes[i] != SD[i]) dict = false;
      if (in_sizes[i] != SA[i]) alph = false;
    }
  }
  if (!dict && !alph) {
    int ix = 0;
    for (int i = 0; i < n_in; ++i)
      if (in_sizes[i] == 33554432 || in_sizes[i] == 134217728) { ix = i; break; }
    dict = (ix == 0);
  }
  const float* x     = (const float*)d_in[dict ? 0 : 8];
  const void*  fr    =               d_in[1];
  const float* L1    = (const float*)d_in[dict ? 2 : 4];
  const float* L2    = (const float*)d_in[dict ? 3 : 5];
  const float* gs    = (const float*)d_in[dict ? 4 : 3];
  const float* gb    = (const float*)d_in[dict ? 5 : 2];
  const float* sa    = (const float*)d_in[dict ? 6 : 7];
  const float* scale = (const float*)d_in[dict ? 7 : 6];
  const float* bias  = (const float*)d_in[dict ? 8 : 0];
  float* out = (float*)d_out;

  const size_t MW_B = (size_t)NDIM * KDIM * 2;    // 33,554,432
  const size_t XH_B = (size_t)8192 * KDIM * 2;    // 67,108,864

  char* ws = (char*)d_ws;
  // ws_size proven >= this layout by rounds 9-17 (T2 path executed).
  f16* mW  = (f16*)ws;
  f16* xh  = (f16*)(ws + MW_B);
  f16* hid = (f16*)(ws + MW_B + XH_B);

  k9_cast_x<<<dim3(16384), dim3(256), 0, stream>>>(x, xh);
  k9_build_m<<<dim3(8192), dim3(256), 0, stream>>>(fr, gs, gb, sa, mW);
  k14_hid<<<dim3(256), dim3(256), 0, stream>>>(xh, L1, hid);
  k18b_main<<<dim3(512), dim3(512), 0, stream>>>(
      xh, mW, hid, L2, scale, bias, out);
}

// Round 19
// 420.645 us; speedup vs baseline: 1.4590x; 1.0113x over previous
//
#include <hip/hip_runtime.h>
#include <stdint.h>

typedef _Float16 f16;
typedef unsigned short u16;
typedef __attribute__((ext_vector_type(8))) _Float16 h16x8;
typedef __attribute__((ext_vector_type(8))) unsigned short u16x8;
typedef __attribute__((ext_vector_type(4))) float f32x4;

#define NDIM  4096
#define KDIM  4096
#define LRDIM 64
#define NTK   128        // KDIM / 32

#define MFMA16(a, b, c) __builtin_amdgcn_mfma_f32_16x16x32_f16((a), (b), (c), 0, 0, 0)

__device__ __forceinline__ float bf2f(u16 b) {
  union { unsigned u; float f; } c; c.u = ((unsigned)b) << 16; return c.f;
}
__device__ __forceinline__ float h2f(u16 b) {
  union { u16 u; f16 h; } c; c.u = b; return (float)c.h;
}
__device__ __forceinline__ h16x8 pack8(float4 a, float4 b) {
  h16x8 w = { (f16)a.x, (f16)a.y, (f16)a.z, (f16)a.w,
              (f16)b.x, (f16)b.y, (f16)b.z, (f16)b.w };
  return w;
}

// async global->LDS, 16B/lane; true addrspacecast (proven green r10-r18).
__device__ __forceinline__ void gll16(const void* g, void* l) {
  __builtin_amdgcn_global_load_lds(
      (const __attribute__((address_space(1))) void*)g,
      (__attribute__((address_space(3))) void*)l,
      16, 0, 0);
}

// ---------------------------------------------------------------------------
// frozen encoding classifier (proven): 0=f16, 1=bf16, 2=f32 halfword layout.
// ---------------------------------------------------------------------------
__device__ int frozen_mode(const void* frozen, int t) {
  const u16* fr = (const u16*)frozen;
  __shared__ int sE[256], sO[256];
  int ce = 0, co = 0;
  for (int j = 0; j < 8; ++j) {
    float ve = fabsf(bf2f(fr[t * 16 + 2 * j]));
    float vo = fabsf(bf2f(fr[t * 16 + 2 * j + 1]));
    if (ve >= 0.05f && ve <= 10.0f) ++ce;
    if (vo >= 0.05f && vo <= 10.0f) ++co;
  }
  sE[t] = ce; sO[t] = co;
  __syncthreads();
  for (int s = 128; s > 0; s >>= 1) {
    if (t < s) { sE[t] += sE[t + s]; sO[t] += sO[t + s]; }
    __syncthreads();
  }
  int te = sE[0], to = sO[0];
  __syncthreads();
  if (to > 1024) return (te > 1024) ? 1 : 2;
  return 0;
}

__device__ __forceinline__ h16x8 build_m8(
    const void* __restrict__ frozen, const float* __restrict__ gs,
    const float* __restrict__ gb, const float* __restrict__ sa,
    int o, int i0, int mode)
{
  size_t fo = (size_t)o * KDIM + i0;
  int gidx = (o >> 3) * 512 + (i0 >> 3);
  float gsf = gs[gidx], gbf = gb[gidx];
  float4 s0 = ((const float4*)(sa + fo))[0];
  float4 s1 = ((const float4*)(sa + fo))[1];
  float sv[8] = { s0.x, s0.y, s0.z, s0.w, s1.x, s1.y, s1.z, s1.w };
  float fv[8];
  if (mode == 2) {
    float4 q0 = ((const float4*)((const float*)frozen + fo))[0];
    float4 q1 = ((const float4*)((const float*)frozen + fo))[1];
    fv[0]=q0.x; fv[1]=q0.y; fv[2]=q0.z; fv[3]=q0.w;
    fv[4]=q1.x; fv[5]=q1.y; fv[6]=q1.z; fv[7]=q1.w;
  } else {
    u16x8 fb = *(const u16x8*)((const u16*)frozen + fo);
#pragma unroll
    for (int j = 0; j < 8; ++j) fv[j] = (mode == 1) ? bf2f(fb[j]) : h2f(fb[j]);
  }
  h16x8 w;
#pragma unroll
  for (int j = 0; j < 8; ++j) w[j] = (f16)(gbf + fv[j] * gsf + sv[j]);
  return w;
}

// ---------------------------------------------------------------------------
// k_prep: fused cast_x (blocks 0..16383) + build_m (blocks 16384..24575).
// Same arithmetic as the two proven kernels; one launch, full-device overlap.
// ---------------------------------------------------------------------------
__global__ __launch_bounds__(256) void k_prep(
    const float* __restrict__ x, const void* __restrict__ frozen,
    const float* __restrict__ gs, const float* __restrict__ gb,
    const float* __restrict__ sa, f16* __restrict__ xh,
    f16* __restrict__ mW)
{
  int b = blockIdx.x;
  if (b < 16384) {
    size_t idx = (size_t)b * 256 + threadIdx.x;
    const float4* xp = (const float4*)x + idx * 2;
    *(h16x8*)(xh + idx * 8) = pack8(xp[0], xp[1]);
  } else {
    int mode = frozen_mode(frozen, threadIdx.x);
    int idx = (b - 16384) * 256 + threadIdx.x;
    int o  = idx >> 9;
    int ig = idx & 511;
    h16x8 w = build_m8(frozen, gs, gb, sa, o, ig * 8, mode);
    *(h16x8*)(mW + (size_t)o * KDIM + ig * 8) = w;
  }
}

// ---------------------------------------------------------------------------
// k14_hid (proven): hid = xh @ L1^T via MFMA, 256 blocks, BM=32.
// ---------------------------------------------------------------------------
__global__ __launch_bounds__(256) void k14_hid(const f16* __restrict__ xh,
                                               const float* __restrict__ L1,
                                               f16* __restrict__ hid)
{
  __shared__ f16 sA[2][32 * 32];
  __shared__ f16 sB[2][64 * 32];
  int t = threadIdx.x;
  int l = t & 63, wid = t >> 6;
  int wr = wid >> 1, wc = wid & 1;
  int brow = blockIdx.x * 32;
  int ar = t >> 2, ac8 = (t & 3) * 8;
  int brw = t >> 2, bc8 = (t & 3) * 8;

  f32x4 acc[2] = {};

  {
    if (t < 128)
      gll16(xh + (size_t)(brow + ar) * KDIM + ac8, &sA[0][ar * 32 + ac8]);
    const float* lp = L1 + (size_t)brw * KDIM + bc8;
    *(h16x8*)&sB[0][brw * 32 + bc8] = pack8(((const float4*)lp)[0], ((const float4*)lp)[1]);
  }

  int cur = 0;
  const int NT = KDIM / 32;
  for (int kt = 0; kt < NT; ++kt) {
    __syncthreads();
    bool pf = (kt + 1 < NT);
    h16x8 wb;
    if (pf) {
      int k0 = (kt + 1) * 32;
      if (t < 128)
        gll16(xh + (size_t)(brow + ar) * KDIM + k0 + ac8, &sA[cur ^ 1][ar * 32 + ac8]);
      const float* lp = L1 + (size_t)brw * KDIM + k0 + bc8;
      wb = pack8(((const float4*)lp)[0], ((const float4*)lp)[1]);
    }
    h16x8 aF, bF[2];
    aF = *(const h16x8*)&sA[cur][(wr * 16 + (l & 15)) * 32 + (l >> 4) * 8];
#pragma unroll
    for (int n = 0; n < 2; ++n)
      bF[n] = *(const h16x8*)&sB[cur][(wc * 32 + n * 16 + (l & 15)) * 32 + (l >> 4) * 8];
#pragma unroll
    for (int n = 0; n < 2; ++n)
      acc[n] = MFMA16(aF, bF[n], acc[n]);
    if (pf)
      *(h16x8*)&sB[cur ^ 1][brw * 32 + bc8] = wb;
    cur ^= 1;
  }

#pragma unroll
  for (int n = 0; n < 2; ++n)
#pragma unroll
    for (int j = 0; j < 4; ++j) {
      int r = wr * 16 + ((l >> 4) << 2) + j;
      int c = wc * 32 + n * 16 + (l & 15);
      hid[(size_t)(brow + r) * LRDIM + c] = (f16)acc[n][j];
    }
}

// ---------------------------------------------------------------------------
// k18c_main: r18's proven kernel with the K-loop sync reduced from 8 barriers
// per tile to 2 barriers + 1 counted gate:
//   E-barrier (end of tile body): all waves' reads of buf[(kt-1)%3] complete
//     (lgkm drained by MFMA consumption) before next iter's stages can
//     overwrite that buffer (same region: (kt+2)%3 == (kt-1)%3).
//   vmcnt(N) + G-barrier: own loads for tile kt landed + rendezvous =>
//     tile kt resident for ALL waves. N = 8 steady (tiles kt+1, kt+2 in
//     flight), 4 at kt=NTK-2, 0 at kt=NTK-1 — never 0 in steady state.
// Compiler now free-schedules 12 ds_reads + 32 MFMAs per tile (fine lgkmcnt
// interleave). Swizzle (src+read, r18-proven), prologue, epilogue unchanged.
// ---------------------------------------------------------------------------
__global__ __launch_bounds__(512) void k18c_main(
    const f16* __restrict__ xh, const f16* __restrict__ mW,
    const f16* __restrict__ hid, const float* __restrict__ L2,
    const float* __restrict__ scale, const float* __restrict__ bias,
    float* __restrict__ out)
{
  __shared__ f16 lds[3][16384];     // 3 x (A[256][32] + B[256][32]) = 96 KB

  int t = threadIdx.x;              // 0..511
  int l = t & 63, wid = t >> 6;     // 8 waves
  int wm = wid >> 2, wn = wid & 3;

  // XCD 2-D chunked mapping (proven r16): 512 blocks = 8 XCDs x 64
  int wg = blockIdx.x;
  int xcd = wg & 7, w = wg >> 3;
  int bm = xcd * 4 + (w & 3);       // 0..31
  int bn = w >> 2;                  // 0..15
  int brow = bm * 256, bcol = bn * 256;

  // stage one K-tile quarter (source-side swizzle: s_g = s_lds ^ ((r>>1)&3))
  auto stage = [&](int q, int kt2, int buf) {
    int u = q * 512 + t;
    if (u < 1024) {
      int sg = (u & 3) ^ ((u >> 3) & 3);
      gll16(xh + (size_t)(brow + (u >> 2)) * KDIM + kt2 * 32 + sg * 8,
            &lds[buf][u * 8]);
    } else {
      int v = u - 1024;
      int sg = (v & 3) ^ ((v >> 3) & 3);
      gll16(mW + (size_t)(bcol + (v >> 2)) * KDIM + kt2 * 32 + sg * 8,
            &lds[buf][8192 + v * 8]);
    }
  };

  // ---- prologue: stage K-tiles 0 (buf0) and 1 (buf1) ----
#pragma unroll
  for (int q = 0; q < 4; ++q) stage(q, 0, 0);
#pragma unroll
  for (int q = 0; q < 4; ++q) stage(q, 1, 1);

  f32x4 acc[8][4] = {};

  // read-side swizzle (lane-constant)
  int X = ((l >> 4) ^ ((l >> 1) & 3)) * 8;

  for (int kt = 0; kt < NTK; ++kt) {
    const f16* A = &lds[kt % 3][0];
    const f16* B = &lds[kt % 3][8192];
    int sb = (kt + 2) % 3;

    // stages for tile kt+2 (safe: E-barrier of iter kt-1 separates these
    // writes from all waves' reads of buf[(kt-1)%3] == buf[sb])
    if (kt + 2 < NTK) {
#pragma unroll
      for (int q = 0; q < 4; ++q) stage(q, kt + 2, sb);
    }

    // residency gate for tile kt
    if (kt < NTK - 2) {
      asm volatile("s_waitcnt vmcnt(8)" ::: "memory");
    } else if (kt == NTK - 2) {
      asm volatile("s_waitcnt vmcnt(4)" ::: "memory");
    } else {
      asm volatile("s_waitcnt vmcnt(0)" ::: "memory");
    }
    __builtin_amdgcn_sched_barrier(0);
    __builtin_amdgcn_s_barrier();   // G: tile kt resident for all waves

    int ar0 = (wm * 128 + (l & 15)) * 32 + X;
    int br0 = (wn * 64  + (l & 15)) * 32 + X;

    h16x8 aF[8], bF[4];
#pragma unroll
    for (int f = 0; f < 8; ++f) aF[f] = *(const h16x8*)&A[ar0 + f * 512];
#pragma unroll
    for (int n = 0; n < 4; ++n) bF[n] = *(const h16x8*)&B[br0 + n * 512];

    __builtin_amdgcn_s_setprio(1);
#pragma unroll
    for (int f = 0; f < 8; ++f)
#pragma unroll
      for (int n = 0; n < 4; ++n)
        acc[f][n] = MFMA16(aF[f], bF[n], acc[f][n]);
    __builtin_amdgcn_s_setprio(0);

    __builtin_amdgcn_s_barrier();   // E: all reads of buf[kt%3] done
  }

  // ---- fused epilogue (byte-identical to r17/r18) ----
  f16* sH  = &lds[0][0];
  f16* sLm = &lds[1][0];
  f16* sLa = &lds[2][0];

#pragma unroll
  for (int q = 0; q < 4; ++q) {
    int u = q * 512 + t;
    gll16(hid + (size_t)(brow + (u >> 3)) * LRDIM + (u & 7) * 8, &sH[u * 8]);
  }
#pragma unroll
  for (int q = 0; q < 4; ++q) {
    int u = q * 512 + t;
    const float* lp = L2 + (size_t)(bcol + (u >> 3)) * LRDIM + (u & 7) * 8;
    *(h16x8*)&sLm[u * 8] = pack8(((const float4*)lp)[0], ((const float4*)lp)[1]);
  }
#pragma unroll
  for (int q = 0; q < 4; ++q) {
    int u = q * 512 + t;
    const float* lp = L2 + (size_t)(NDIM + bcol + (u >> 3)) * LRDIM + (u & 7) * 8;
    *(h16x8*)&sLa[u * 8] = pack8(((const float4*)lp)[0], ((const float4*)lp)[1]);
  }
  __syncthreads();                  // full drain before reads

  float sc[4], bi[4];
#pragma unroll
  for (int n = 0; n < 4; ++n) {
    int o = bcol + wn * 64 + n * 16 + (l & 15);
    sc[n] = scale[o];
    bi[n] = bias[o];
  }

  // pass 1: mul = hid @ L2[0:4096]^T + scale ; acc <- mul * acc
  {
    h16x8 lB[4][2];
#pragma unroll
    for (int n = 0; n < 4; ++n)
#pragma unroll
      for (int kk = 0; kk < 2; ++kk)
        lB[n][kk] = *(const h16x8*)&sLm[(wn * 64 + n * 16 + (l & 15)) * 64 + kk * 32 + (l >> 4) * 8];
#pragma unroll
    for (int f = 0; f < 8; ++f) {
      h16x8 h0 = *(const h16x8*)&sH[(wm * 128 + f * 16 + (l & 15)) * 64 + (l >> 4) * 8];
      h16x8 h1 = *(const h16x8*)&sH[(wm * 128 + f * 16 + (l & 15)) * 64 + 32 + (l >> 4) * 8];
      f32x4 mm[4];
#pragma unroll
      for (int n = 0; n < 4; ++n) {
        f32x4 mi = { sc[n], sc[n], sc[n], sc[n] };
        mm[n] = mi;
      }
#pragma unroll
      for (int n = 0; n < 4; ++n) {
        mm[n] = MFMA16(h0, lB[n][0], mm[n]);
        mm[n] = MFMA16(h1, lB[n][1], mm[n]);
      }
#pragma unroll
      for (int n = 0; n < 4; ++n)
        acc[f][n] *= mm[n];
    }
  }

  // pass 2: add = hid @ L2[4096:8192]^T + bias ; out = add + acc
  {
    h16x8 lB[4][2];
#pragma unroll
    for (int n = 0; n < 4; ++n)
#pragma unroll
      for (int kk = 0; kk < 2; ++kk)
        lB[n][kk] = *(const h16x8*)&sLa[(wn * 64 + n * 16 + (l & 15)) * 64 + kk * 32 + (l >> 4) * 8];
#pragma unroll
    for (int f = 0; f < 8; ++f) {
      h16x8 h0 = *(const h16x8*)&sH[(wm * 128 + f * 16 + (l & 15)) * 64 + (l >> 4) * 8];
      h16x8 h1 = *(const h16x8*)&sH[(wm * 128 + f * 16 + (l & 15)) * 64 + 32 + (l >> 4) * 8];
      f32x4 aa[4];
#pragma unroll
      for (int n = 0; n < 4; ++n) {
        f32x4 mi = { bi[n], bi[n], bi[n], bi[n] };
        aa[n] = mi;
      }
#pragma unroll
      for (int n = 0; n < 4; ++n) {
        aa[n] = MFMA16(h0, lB[n][0], aa[n]);
        aa[n] = MFMA16(h1, lB[n][1], aa[n]);
      }
      int rbase = brow + wm * 128 + f * 16 + ((l >> 4) << 2);
#pragma unroll
      for (int n = 0; n < 4; ++n) {
        int c = bcol + wn * 64 + n * 16 + (l & 15);
        f32x4 v = aa[n] + acc[f][n];
#pragma unroll
        for (int j = 0; j < 4; ++j)
          out[(size_t)(rbase + j) * NDIM + c] = v[j];
      }
    }
  }
}

// ---------------------------------------------------------------------------
extern "C" void kernel_launch(void* const* d_in, const int* in_sizes, int n_in,
                              void* d_out, int out_size, void* d_ws, size_t ws_size,
                              hipStream_t stream)
{
  const int SD[9] = {33554432,16777216,262144,524288,262144,262144,16777216,4096,4096};
  const int SA[9] = {4096,16777216,262144,262144,262144,524288,4096,16777216,33554432};
  bool dict = (n_in == 9), alph = (n_in == 9);
  if (n_in == 9) {
    for (int i = 0; i < 9; ++i) {
      if (in_sizes[i] != SD[i]) dict = false;
      if (in_sizes[i] != SA[i]) alph = false;
    }
  }
  if (!dict && !alph) {
    int ix = 0;
    for (int i = 0; i < n_in; ++i)
      if (in_sizes[i] == 33554432 || in_sizes[i] == 134217728) { ix = i; break; }
    dict = (ix == 0);
  }
  const float* x     = (const float*)d_in[dict ? 0 : 8];
  const void*  fr    =               d_in[1];
  const float* L1    = (const float*)d_in[dict ? 2 : 4];
  const float* L2    = (const float*)d_in[dict ? 3 : 5];
  const float* gs    = (const float*)d_in[dict ? 4 : 3];
  const float* gb    = (const float*)d_in[dict ? 5 : 2];
  const float* sa    = (const float*)d_in[dict ? 6 : 7];
  const float* scale = (const float*)d_in[dict ? 7 : 6];
  const float* bias  = (const float*)d_in[dict ? 8 : 0];
  float* out = (float*)d_out;

  const size_t MW_B = (size_t)NDIM * KDIM * 2;    // 33,554,432
  const size_t XH_B = (size_t)8192 * KDIM * 2;    // 67,108,864

  char* ws = (char*)d_ws;
  // ws_size proven >= this layout by rounds 9-18 (T2 path executed).
  f16* mW  = (f16*)ws;
  f16* xh  = (f16*)(ws + MW_B);
  f16* hid = (f16*)(ws + MW_B + XH_B);

  k_prep<<<dim3(24576), dim3(256), 0, stream>>>(x, fr, gs, gb, sa, xh, mW);
  k14_hid<<<dim3(256), dim3(256), 0, stream>>>(xh, L1, hid);
  k18c_main<<<dim3(512), dim3(512), 0, stream>>>(
      xh, mW, hid, L2, scale, bias, out);
}